// Round 4
// baseline (124.892 us; speedup 1.0000x reference)
//
#include <hip/hip_runtime.h>
#include <math.h>

// B=1, C=256, N=16^3=4096 tokens, 16 groups, 4 heads, d=64.
#define N_TOK 4096
#define C_CH  256
#define SPLITS 4

typedef short bf16x8 __attribute__((ext_vector_type(8)));
typedef float f32x4  __attribute__((ext_vector_type(4)));
typedef unsigned short u16;

__device__ __forceinline__ u16 f2bf(float f) {
    union { float f; unsigned u; } v; v.f = f;
    unsigned r = v.u + 0x7FFF + ((v.u >> 16) & 1);   // RNE
    return (u16)(r >> 16);
}
__device__ __forceinline__ float bf2f(u16 b) {
    union { unsigned u; float f; } v; v.u = ((unsigned)b) << 16;
    return v.f;
}
// pack two floats to bf16 pair (truncation) in one v_perm_b32
__device__ __forceinline__ unsigned packtr(float a, float b) {
    union { float f; unsigned u; } ua, ub; ua.f = a; ub.f = b;
    return __builtin_amdgcn_perm(ub.u, ua.u, 0x07060302u);  // lo=hi16(a), hi=hi16(b)
}

// ---------------- L1: weight convert (blocks 0..1023) + GN partials (1024..1279)
// Q rows pre-scaled by 1/8 (qk scale) * log2(e) (exp->exp2 fold).
__global__ __launch_bounds__(256) void prep(const float* __restrict__ wqkv,
                                            const float* __restrict__ wproj,
                                            const float* __restrict__ x,
                                            u16* __restrict__ wq, u16* __restrict__ wp,
                                            float2* __restrict__ part) {
    __shared__ float rs[4], rss[4];
    if (blockIdx.x < 1024) {
        int i = blockIdx.x * 256 + threadIdx.x;          // 262144 threads
        if (i < 196608) {
            int row = i >> 8;
            float s = ((row % 192) < 64) ? 0.18033688f : 1.0f;  // 0.125*log2(e) for Q
            wq[i] = f2bf(wqkv[i] * s);
        } else {
            wp[i - 196608] = f2bf(wproj[i - 196608]);
        }
    } else {
        const int b = blockIdx.x - 1024, tid = threadIdx.x;
        const int lane = tid & 63, wave = tid >> 6;
        const float4* xp = (const float4*)x + b * 1024;
        float s = 0.f, ss = 0.f;
#pragma unroll
        for (int k = 0; k < 4; ++k) {
            float4 v = xp[tid + k * 256];
            s  += v.x + v.y + v.z + v.w;
            ss += v.x * v.x + v.y * v.y + v.z * v.z + v.w * v.w;
        }
#pragma unroll
        for (int off = 1; off < 64; off <<= 1) {
            s  += __shfl_xor(s, off, 64);
            ss += __shfl_xor(ss, off, 64);
        }
        if (lane == 0) { rs[wave] = s; rss[wave] = ss; }
        __syncthreads();
        if (tid == 0) part[b] = make_float2(rs[0]+rs[1]+rs[2]+rs[3], rss[0]+rss[1]+rss[2]+rss[3]);
    }
}

// ---------------- L2: fused GroupNorm + QKV GEMM ----------------------------
// Stages the normalized/transposed 64-tok x 256-ch B-panel once in LDS
// (XOR-swizzled), then MFMA against bf16 weights. Each blockIdx.y produces one
// clean 64x64 tile for exactly one of QT/KTm/Vc: y%3 = Q/K/V, y/3 = head,
// in-block row = c. Q/K: packed uint2 stores; V: LDS transpose + uint4 stores.
__global__ __launch_bounds__(256) void qkv_gemm(const u16* __restrict__ wq,
                                                const float* __restrict__ x,
                                                const float2* __restrict__ part,
                                                const float* __restrict__ gamma,
                                                const float* __restrict__ beta,
                                                u16* __restrict__ QT,
                                                u16* __restrict__ KTm,
                                                u16* __restrict__ Vc) {
    const int nb = blockIdx.x * 64;
    const int tid = threadIdx.x;
    const int wave = tid >> 6, lane = tid & 63;
    const int quad = lane >> 4, low = lane & 15;
    const int mo = blockIdx.y * 64 + wave * 16;

    __shared__ __align__(16) u16 Xs[64 * 256];  // [tok][ch], XOR-swizzled by tok&7
    __shared__ float sca[256], scb[256];

    {   // per-channel affine: a = rstd*gamma, b = beta - mu*a (redundant per block)
        const int ch = tid, g = ch >> 4;
        float s = 0.f, ss = 0.f;
#pragma unroll
        for (int j = 0; j < 16; ++j) { float2 p = part[g * 16 + j]; s += p.x; ss += p.y; }
        float mu = s * (1.f / 65536.f);
        float var = ss * (1.f / 65536.f) - mu * mu;
        float a = rsqrtf(var + 1e-5f) * gamma[ch];
        sca[ch] = a; scb[ch] = beta[ch] - mu * a;
    }
    __syncthreads();

    // stage: thread owns token=lane, channel-groups wave*8+i (i<8); 8-ch chunk each
#pragma unroll
    for (int i = 0; i < 8; ++i) {
        const int g = wave * 8 + i;               // 0..31
        u16 pk[8];
#pragma unroll
        for (int j = 0; j < 8; ++j) {
            const int ch = g * 8 + j;
            pk[j] = f2bf(x[ch * N_TOK + nb + lane] * sca[ch] + scb[ch]);
        }
        *(uint4*)(Xs + lane * 256 + ((g ^ (lane & 7)) * 8)) = *(const uint4*)pk;
    }
    __syncthreads();

    f32x4 acc[4] = {f32x4{0,0,0,0}, f32x4{0,0,0,0}, f32x4{0,0,0,0}, f32x4{0,0,0,0}};
#pragma unroll
    for (int kc = 0; kc < 8; ++kc) {
        bf16x8 af = *(const bf16x8*)(wq + (mo + low) * 256 + kc * 32 + quad * 8);
#pragma unroll
        for (int nt = 0; nt < 4; ++nt) {
            bf16x8 bf_ = *(const bf16x8*)(Xs + (nt * 16 + low) * 256 +
                                          (((kc * 4 + quad) ^ (low & 7)) * 8));
            acc[nt] = __builtin_amdgcn_mfma_f32_16x16x32_bf16(af, bf_, acc[nt], 0, 0, 0);
        }
    }

    // ---- epilogue: one 64x64 tile per block ----
    const int kind = blockIdx.y % 3;              // 0=Q, 1=K, 2=V
    const int head = blockIdx.y / 3;
    const int crow = wave * 16 + quad * 4;        // in-block output row (= c)

    if (kind < 2) {
        // token-major [head][tok][c]: 4 consecutive c per thread -> uint2 store
        u16* dst = (kind == 0 ? QT : KTm) + head * (N_TOK * 64);
#pragma unroll
        for (int nt = 0; nt < 4; ++nt) {
            int tok = nb + nt * 16 + low;
            u16 q4[4];
#pragma unroll
            for (int r = 0; r < 4; ++r) q4[r] = f2bf(acc[nt][r]);
            *(uint2*)(dst + tok * 64 + crow) = *(const uint2*)q4;
        }
    } else {
        // channel-major [head][c][tok]: transpose through LDS, coalesced uint4 out
        __syncthreads();                          // Xs MFMA reads complete
        u16* Ts = Xs;                             // reuse as [64][72] (144B rows, 16B-aligned)
#pragma unroll
        for (int nt = 0; nt < 4; ++nt) {
            int tokl = nt * 16 + low;
#pragma unroll
            for (int r = 0; r < 4; ++r)
                Ts[(crow + r) * 72 + tokl] = f2bf(acc[nt][r]);
        }
        __syncthreads();
        u16* dst = Vc + head * (64 * N_TOK) + nb;
#pragma unroll
        for (int i = 0; i < 2; ++i) {
            int idx = i * 256 + tid;
            int c = idx >> 3, ch = idx & 7;
            uint4 v = *(const uint4*)(Ts + c * 72 + ch * 8);
            *(uint4*)(dst + c * N_TOK + ch * 8) = v;
        }
    }
}

// ---------------- L3: flash-lite attention, exp2 softmax, l via ones-MFMA ---
// Double-buffered K/V staging, ONE barrier per tile. Each wave: 32 queries x
// 64-key tiles; K-split over blockIdx.z (1024 keys each).
__global__ __launch_bounds__(256, 2) void attn_kernel(const u16* __restrict__ QT,
                                                      const u16* __restrict__ KTm,
                                                      const u16* __restrict__ Vc,
                                                      u16* __restrict__ Op,
                                                      float* __restrict__ Lp) {
    const int head = blockIdx.y, split = blockIdx.z;
    const int qb   = blockIdx.x * 128;
    const int tid  = threadIdx.x;
    const int wave = tid >> 6, lane = tid & 63;
    const int quad = lane >> 4, low = lane & 15;

    const u16* Qh = QT  + head * N_TOK * 64;
    const u16* Kh = KTm + head * N_TOK * 64 + split * 1024 * 64;
    const u16* Vh = Vc  + head * 64 * N_TOK + split * 1024;

    __shared__ u16 Ks[2][64 * 64];   // [s][c], 8-short chunks XOR-swizzled by s&7
    __shared__ u16 Vs[2][64 * 64];   // [c][s], swizzled by c&7
    __shared__ u16 Ps[4 * 32 * 64];  // per-wave [t][s], swizzled by t&7
    u16* Pw = Ps + wave * 2048;

    bf16x8 ones;
#pragma unroll
    for (int i = 0; i < 8; ++i) ones[i] = (short)0x3F80;

    // Q B-fragments (n=t, k=c), loaded once (scale+log2e folded into Q weights)
    bf16x8 bq[2][2];
#pragma unroll
    for (int tn = 0; tn < 2; ++tn)
#pragma unroll
        for (int kh = 0; kh < 2; ++kh)
            bq[tn][kh] = *(const bf16x8*)(Qh + (qb + wave * 32 + tn * 16 + low) * 64 + kh * 32 + quad * 8);

    f32x4 oa[2][4], lC[2];
#pragma unroll
    for (int mt = 0; mt < 2; ++mt) {
        lC[mt] = f32x4{0,0,0,0};
#pragma unroll
        for (int cn = 0; cn < 4; ++cn) oa[mt][cn] = f32x4{0,0,0,0};
    }

    // staging: 512 16B chunks each; thread owns rows sA, sA+32, chunk gA
    const int sA = tid >> 3, gA = tid & 7;
    const int swA = ((gA ^ (sA & 7)) * 8);
    const int swB = ((gA ^ ((sA + 32) & 7)) * 8);
    uint4 pk0 = *(const uint4*)(Kh + sA * 64 + gA * 8);
    uint4 pk1 = *(const uint4*)(Kh + (sA + 32) * 64 + gA * 8);
    uint4 pv0 = *(const uint4*)(Vh + sA * N_TOK + gA * 8);
    uint4 pv1 = *(const uint4*)(Vh + (sA + 32) * N_TOK + gA * 8);
    *(uint4*)(Ks[0] + sA * 64 + swA) = pk0;
    *(uint4*)(Ks[0] + (sA + 32) * 64 + swB) = pk1;
    *(uint4*)(Vs[0] + sA * 64 + swA) = pv0;
    *(uint4*)(Vs[0] + (sA + 32) * 64 + swB) = pv1;
    pk0 = *(const uint4*)(Kh + (64 + sA) * 64 + gA * 8);
    pk1 = *(const uint4*)(Kh + (64 + sA + 32) * 64 + gA * 8);
    pv0 = *(const uint4*)(Vh + sA * N_TOK + 64 + gA * 8);
    pv1 = *(const uint4*)(Vh + (sA + 32) * N_TOK + 64 + gA * 8);

    const int low7 = low & 7;

    for (int kt = 0; kt < 16; ++kt) {
        const int cur = kt & 1;
        const u16* Kc = Ks[cur];
        const u16* Vu = Vs[cur];
        __syncthreads();   // buf[cur] staged & visible; prior reads of buf[cur^1] done
        if (kt < 15) {     // write prefetched tile kt+1 into the other buffer
            u16* Kn = Ks[cur ^ 1]; u16* Vn = Vs[cur ^ 1];
            *(uint4*)(Kn + sA * 64 + swA) = pk0;
            *(uint4*)(Kn + (sA + 32) * 64 + swB) = pk1;
            *(uint4*)(Vn + sA * 64 + swA) = pv0;
            *(uint4*)(Vn + (sA + 32) * 64 + swB) = pv1;
            if (kt < 14) { // issue loads for tile kt+2
                int sb2 = (kt + 2) * 64;
                pk0 = *(const uint4*)(Kh + (sb2 + sA) * 64 + gA * 8);
                pk1 = *(const uint4*)(Kh + (sb2 + sA + 32) * 64 + gA * 8);
                pv0 = *(const uint4*)(Vh + sA * N_TOK + sb2 + gA * 8);
                pv1 = *(const uint4*)(Vh + (sA + 32) * N_TOK + sb2 + gA * 8);
            }
        }

        // ---- S^T: C[m=s][n=t] = K A-frag x Q B-frag --------------------------
        f32x4 sa[4][2];
#pragma unroll
        for (int sm = 0; sm < 4; ++sm)
#pragma unroll
            for (int tn = 0; tn < 2; ++tn) sa[sm][tn] = f32x4{0,0,0,0};
#pragma unroll
        for (int kh = 0; kh < 2; ++kh)
#pragma unroll
            for (int sm = 0; sm < 4; ++sm) {
                bf16x8 ak = *(const bf16x8*)(Kc + (sm * 16 + low) * 64 + (((quad + 4 * kh) ^ low7) * 8));
#pragma unroll
                for (int tn = 0; tn < 2; ++tn)
                    sa[sm][tn] = __builtin_amdgcn_mfma_f32_16x16x32_bf16(ak, bq[tn][kh], sa[sm][tn], 0, 0, 0);
            }

        // ---- P = exp2(S) (log2e pre-folded), packed b64 stores into Pw[t][s]
#pragma unroll
        for (int sm = 0; sm < 4; ++sm)
#pragma unroll
            for (int tn = 0; tn < 2; ++tn) {
                float p0 = exp2f(sa[sm][tn][0]);
                float p1 = exp2f(sa[sm][tn][1]);
                float p2 = exp2f(sa[sm][tn][2]);
                float p3 = exp2f(sa[sm][tn][3]);
                uint2 pk; pk.x = packtr(p0, p1); pk.y = packtr(p2, p3);
                int t = tn * 16 + low;
                int sw = ((sm * 2 + (quad >> 1)) ^ low7);
                *(uint2*)(Pw + t * 64 + sw * 8 + (quad & 1) * 4) = pk;
            }
        asm volatile("s_waitcnt lgkmcnt(0)" ::: "memory");  // wave-private P round-trip

        // ---- O += P V^T, l += P 1 ----
#pragma unroll
        for (int kh = 0; kh < 2; ++kh) {
            bf16x8 ap0 = *(const bf16x8*)(Pw + (low) * 64      + (((quad + 4 * kh) ^ low7) * 8));
            bf16x8 ap1 = *(const bf16x8*)(Pw + (16 + low) * 64 + (((quad + 4 * kh) ^ low7) * 8));
            lC[0] = __builtin_amdgcn_mfma_f32_16x16x32_bf16(ap0, ones, lC[0], 0, 0, 0);
            lC[1] = __builtin_amdgcn_mfma_f32_16x16x32_bf16(ap1, ones, lC[1], 0, 0, 0);
#pragma unroll
            for (int cn = 0; cn < 4; ++cn) {
                bf16x8 bv = *(const bf16x8*)(Vu + (cn * 16 + low) * 64 + (((quad + 4 * kh) ^ low7) * 8));
                oa[0][cn] = __builtin_amdgcn_mfma_f32_16x16x32_bf16(ap0, bv, oa[0][cn], 0, 0, 0);
                oa[1][cn] = __builtin_amdgcn_mfma_f32_16x16x32_bf16(ap1, bv, oa[1][cn], 0, 0, 0);
            }
        }
    }

    // ---- epilogue: l stores, then O transposed through dead Pw -> dense stores
    const int sh = (split * 4 + head) * N_TOK;
#pragma unroll
    for (int mt = 0; mt < 2; ++mt)
#pragma unroll
        for (int r = 0; r < 4; ++r) {
            int t = qb + wave * 32 + mt * 16 + quad * 4 + r;
            if (low == 0) Lp[sh + t] = lC[mt][r];
        }
    // pack O rows into Pw[32][64], 8-u16 chunks swizzled by row&7 (bank-balanced)
#pragma unroll
    for (int mt = 0; mt < 2; ++mt)
#pragma unroll
        for (int cn = 0; cn < 4; ++cn) {
            int c = cn * 16 + low;
            int chunk = c >> 3, cl = c & 7;
#pragma unroll
            for (int r = 0; r < 4; ++r) {
                int tr = mt * 16 + quad * 4 + r;
                Pw[tr * 64 + ((chunk ^ (tr & 7)) * 8) + cl] = f2bf(oa[mt][cn][r]);
            }
        }
    asm volatile("s_waitcnt lgkmcnt(0)" ::: "memory");  // wave-private round-trip
    {
        const int r8 = lane >> 3, ch = lane & 7;
#pragma unroll
        for (int it = 0; it < 4; ++it) {
            int row = it * 8 + r8;
            uint4 v = *(const uint4*)(Pw + row * 64 + ((ch ^ (row & 7)) * 8));
            *(uint4*)(Op + (sh + qb + wave * 32 + row) * 64 + ch * 8) = v;
        }
    }
}

// ---------------- L4: combine partials (into LDS hT tile) + proj GEMM + bias
// ---------------- + residual (fp32 out). 32-token x FULL-256-row blocks ->
// ---------------- combine runs exactly once per token tile.
__global__ __launch_bounds__(256) void proj_gemm(const u16* __restrict__ wp,
                                                 const u16* __restrict__ Op,
                                                 const float* __restrict__ Lp,
                                                 const float* __restrict__ bias,
                                                 const float* __restrict__ xres,
                                                 float* __restrict__ out) {
    const int nb = blockIdx.x * 32;
    const int mo = (threadIdx.x >> 6) * 64;       // wave owns 64 output rows
    const int lane = threadIdx.x & 63;
    const int quad = lane >> 4, low = lane & 15;

    __shared__ u16 hT[32 * 264];   // [t][c], row stride 264 shorts -> 2-way banks, free

    // combine: 1024 chunks (32 tok x 32 eight-channel chunks), 4 per thread
#pragma unroll
    for (int i = 0; i < 4; ++i) {
        int idx = i * 256 + threadIdx.x;
        int t = idx >> 5, cc = idx & 31;
        int head = cc >> 3;
        int tok = nb + t;
        float l = 0.f;
        float o[8] = {0.f,0.f,0.f,0.f,0.f,0.f,0.f,0.f};
#pragma unroll
        for (int sp = 0; sp < SPLITS; ++sp) {
            int b = (sp * 4 + head) * N_TOK + tok;
            l += Lp[b];
            uint4 pv = *(const uint4*)(Op + b * 64 + (cc & 7) * 8);
            const u16* ps = (const u16*)&pv;
#pragma unroll
            for (int j = 0; j < 8; ++j) o[j] += bf2f(ps[j]);
        }
        float rl = 1.f / l;
        u16 res[8];
#pragma unroll
        for (int j = 0; j < 8; ++j) res[j] = f2bf(o[j] * rl);
        *(uint4*)(hT + t * 264 + cc * 8) = *(const uint4*)res;
    }
    __syncthreads();

    f32x4 acc[4][2] = {{f32x4{0,0,0,0}, f32x4{0,0,0,0}}, {f32x4{0,0,0,0}, f32x4{0,0,0,0}},
                       {f32x4{0,0,0,0}, f32x4{0,0,0,0}}, {f32x4{0,0,0,0}, f32x4{0,0,0,0}}};
#pragma unroll
    for (int kc = 0; kc < 8; ++kc) {
        bf16x8 b0 = *(const bf16x8*)(hT + (low) * 264      + kc * 32 + quad * 8);
        bf16x8 b1 = *(const bf16x8*)(hT + (16 + low) * 264 + kc * 32 + quad * 8);
#pragma unroll
        for (int mt = 0; mt < 4; ++mt) {
            bf16x8 af = *(const bf16x8*)(wp + (mo + mt * 16 + low) * 256 + kc * 32 + quad * 8);
            acc[mt][0] = __builtin_amdgcn_mfma_f32_16x16x32_bf16(af, b0, acc[mt][0], 0, 0, 0);
            acc[mt][1] = __builtin_amdgcn_mfma_f32_16x16x32_bf16(af, b1, acc[mt][1], 0, 0, 0);
        }
    }
#pragma unroll
    for (int mt = 0; mt < 4; ++mt)
#pragma unroll
        for (int r = 0; r < 4; ++r) {
            int o = mo + mt * 16 + quad * 4 + r;
            float bv = bias[o];
#pragma unroll
            for (int nt = 0; nt < 2; ++nt) {
                int tok = nb + nt * 16 + low;
                out[o * N_TOK + tok] = acc[mt][nt][r] + bv + xres[o * N_TOK + tok];
            }
        }
}

extern "C" void kernel_launch(void* const* d_in, const int* in_sizes, int n_in,
                              void* d_out, int out_size, void* d_ws, size_t ws_size,
                              hipStream_t stream) {
    const float* x      = (const float*)d_in[0];
    const float* gamma  = (const float*)d_in[1];
    const float* beta   = (const float*)d_in[2];
    const float* w_qkv  = (const float*)d_in[3];
    const float* w_proj = (const float*)d_in[4];
    const float* b_proj = (const float*)d_in[5];
    float* out = (float*)d_out;

    // ws layout (bytes).
    char* base = (char*)d_ws;
    u16*    Op    = (u16*)base;                        // 4*4*4096*64*2  = 8,388,608
    float*  Lp    = (float*)(base + 8388608);          // 4*4*4096*4     =   262,144
    float2* part  = (float2*)(base + 8654848);         // 4 KB
    u16*    wq    = (u16*)(base + 8658944);            // 768*256*2      =   393,216
    u16*    wp    = (u16*)(base + 9052160);            // 256*256*2      =   131,072
    u16*    QT    = (u16*)(base + 9183232);            // 2 MB
    u16*    KTm   = (u16*)(base + 11280384);           // 2 MB
    u16*    Vc    = (u16*)(base + 13377536);           // 2 MB (end ~15.5 MB)

    prep      <<<1280, 256, 0, stream>>>(w_qkv, w_proj, x, wq, wp, part);
    qkv_gemm  <<<dim3(64, 12), 256, 0, stream>>>(wq, x, part, gamma, beta, QT, KTm, Vc);
    attn_kernel<<<dim3(32, 4, SPLITS), 256, 0, stream>>>(QT, KTm, Vc, Op, Lp);
    proj_gemm <<<128, 256, 0, stream>>>(wp, Op, Lp, b_proj, x, out);
}

// Round 5
// 119.017 us; speedup vs baseline: 1.0494x; 1.0494x over previous
//
#include <hip/hip_runtime.h>
#include <math.h>

// B=1, C=256, N=16^3=4096 tokens, 16 groups, 4 heads, d=64.
#define N_TOK 4096
#define C_CH  256
#define SPLITS 4

typedef short bf16x8 __attribute__((ext_vector_type(8)));
typedef float f32x4  __attribute__((ext_vector_type(4)));
typedef unsigned short u16;

__device__ __forceinline__ u16 f2bf(float f) {
    union { float f; unsigned u; } v; v.f = f;
    unsigned r = v.u + 0x7FFF + ((v.u >> 16) & 1);   // RNE
    return (u16)(r >> 16);
}
__device__ __forceinline__ float bf2f(u16 b) {
    union { unsigned u; float f; } v; v.u = ((unsigned)b) << 16;
    return v.f;
}
// pack two floats to bf16 pair (truncation) in one v_perm_b32
__device__ __forceinline__ unsigned packtr(float a, float b) {
    union { float f; unsigned u; } ua, ub; ua.f = a; ub.f = b;
    return __builtin_amdgcn_perm(ub.u, ua.u, 0x07060302u);  // lo=hi16(a), hi=hi16(b)
}

// ---------------- L1: weight convert (blocks 0..1023) + GN partials (1024..1279)
// Q rows pre-scaled by 1/8 (qk scale) * log2(e) (exp->exp2 fold).
__global__ __launch_bounds__(256) void prep(const float* __restrict__ wqkv,
                                            const float* __restrict__ wproj,
                                            const float* __restrict__ x,
                                            u16* __restrict__ wq, u16* __restrict__ wp,
                                            float2* __restrict__ part) {
    __shared__ float rs[4], rss[4];
    if (blockIdx.x < 1024) {
        int i = blockIdx.x * 256 + threadIdx.x;          // 262144 threads
        if (i < 196608) {
            int row = i >> 8;
            float s = ((row % 192) < 64) ? 0.18033688f : 1.0f;  // 0.125*log2(e) for Q
            wq[i] = f2bf(wqkv[i] * s);
        } else {
            wp[i - 196608] = f2bf(wproj[i - 196608]);
        }
    } else {
        const int b = blockIdx.x - 1024, tid = threadIdx.x;
        const int lane = tid & 63, wave = tid >> 6;
        const float4* xp = (const float4*)x + b * 1024;
        float s = 0.f, ss = 0.f;
#pragma unroll
        for (int k = 0; k < 4; ++k) {
            float4 v = xp[tid + k * 256];
            s  += v.x + v.y + v.z + v.w;
            ss += v.x * v.x + v.y * v.y + v.z * v.z + v.w * v.w;
        }
#pragma unroll
        for (int off = 1; off < 64; off <<= 1) {
            s  += __shfl_xor(s, off, 64);
            ss += __shfl_xor(ss, off, 64);
        }
        if (lane == 0) { rs[wave] = s; rss[wave] = ss; }
        __syncthreads();
        if (tid == 0) part[b] = make_float2(rs[0]+rs[1]+rs[2]+rs[3], rss[0]+rss[1]+rss[2]+rss[3]);
    }
}

// ---------------- L2: fused GroupNorm + QKV GEMM ----------------------------
// Stages the normalized/transposed 64-tok x 256-ch B-panel once in LDS
// (XOR-swizzled), then MFMA against bf16 weights. Each blockIdx.y produces one
// clean 64x64 tile for exactly one of QT/KTm/Vc: y%3 = Q/K/V, y/3 = head,
// in-block row = c. Q/K: packed uint2 stores; V: LDS transpose + uint4 stores.
__global__ __launch_bounds__(256) void qkv_gemm(const u16* __restrict__ wq,
                                                const float* __restrict__ x,
                                                const float2* __restrict__ part,
                                                const float* __restrict__ gamma,
                                                const float* __restrict__ beta,
                                                u16* __restrict__ QT,
                                                u16* __restrict__ KTm,
                                                u16* __restrict__ Vc) {
    const int nb = blockIdx.x * 64;
    const int tid = threadIdx.x;
    const int wave = tid >> 6, lane = tid & 63;
    const int quad = lane >> 4, low = lane & 15;
    const int mo = blockIdx.y * 64 + wave * 16;

    __shared__ __align__(16) u16 Xs[64 * 256];  // [tok][ch], XOR-swizzled by tok&7
    __shared__ float sca[256], scb[256];

    {   // per-channel affine: a = rstd*gamma, b = beta - mu*a (redundant per block)
        const int ch = tid, g = ch >> 4;
        float s = 0.f, ss = 0.f;
#pragma unroll
        for (int j = 0; j < 16; ++j) { float2 p = part[g * 16 + j]; s += p.x; ss += p.y; }
        float mu = s * (1.f / 65536.f);
        float var = ss * (1.f / 65536.f) - mu * mu;
        float a = rsqrtf(var + 1e-5f) * gamma[ch];
        sca[ch] = a; scb[ch] = beta[ch] - mu * a;
    }
    __syncthreads();

    // stage: thread owns token=lane, channel-groups wave*8+i (i<8); 8-ch chunk each
#pragma unroll
    for (int i = 0; i < 8; ++i) {
        const int g = wave * 8 + i;               // 0..31
        u16 pk[8];
#pragma unroll
        for (int j = 0; j < 8; ++j) {
            const int ch = g * 8 + j;
            pk[j] = f2bf(x[ch * N_TOK + nb + lane] * sca[ch] + scb[ch]);
        }
        *(uint4*)(Xs + lane * 256 + ((g ^ (lane & 7)) * 8)) = *(const uint4*)pk;
    }
    __syncthreads();

    f32x4 acc[4] = {f32x4{0,0,0,0}, f32x4{0,0,0,0}, f32x4{0,0,0,0}, f32x4{0,0,0,0}};
#pragma unroll
    for (int kc = 0; kc < 8; ++kc) {
        bf16x8 af = *(const bf16x8*)(wq + (mo + low) * 256 + kc * 32 + quad * 8);
#pragma unroll
        for (int nt = 0; nt < 4; ++nt) {
            bf16x8 bf_ = *(const bf16x8*)(Xs + (nt * 16 + low) * 256 +
                                          (((kc * 4 + quad) ^ (low & 7)) * 8));
            acc[nt] = __builtin_amdgcn_mfma_f32_16x16x32_bf16(af, bf_, acc[nt], 0, 0, 0);
        }
    }

    // ---- epilogue: one 64x64 tile per block ----
    const int kind = blockIdx.y % 3;              // 0=Q, 1=K, 2=V
    const int head = blockIdx.y / 3;
    const int crow = wave * 16 + quad * 4;        // in-block output row (= c)

    if (kind < 2) {
        // token-major [head][tok][c]: 4 consecutive c per thread -> uint2 store
        u16* dst = (kind == 0 ? QT : KTm) + head * (N_TOK * 64);
#pragma unroll
        for (int nt = 0; nt < 4; ++nt) {
            int tok = nb + nt * 16 + low;
            u16 q4[4];
#pragma unroll
            for (int r = 0; r < 4; ++r) q4[r] = f2bf(acc[nt][r]);
            *(uint2*)(dst + tok * 64 + crow) = *(const uint2*)q4;
        }
    } else {
        // channel-major [head][c][tok]: transpose through LDS, coalesced uint4 out
        __syncthreads();                          // Xs MFMA reads complete
        u16* Ts = Xs;                             // reuse as [64][72] (144B rows, 16B-aligned)
#pragma unroll
        for (int nt = 0; nt < 4; ++nt) {
            int tokl = nt * 16 + low;
#pragma unroll
            for (int r = 0; r < 4; ++r)
                Ts[(crow + r) * 72 + tokl] = f2bf(acc[nt][r]);
        }
        __syncthreads();
        u16* dst = Vc + head * (64 * N_TOK) + nb;
#pragma unroll
        for (int i = 0; i < 2; ++i) {
            int idx = i * 256 + tid;
            int c = idx >> 3, ch = idx & 7;
            uint4 v = *(const uint4*)(Ts + c * 72 + ch * 8);
            *(uint4*)(dst + c * N_TOK + ch * 8) = v;
        }
    }
}

// ---------------- L3: flash-lite attention, exp2 softmax, l via ones-MFMA ---
// Double-buffered K/V staging, ONE barrier per tile. Each wave: 32 queries x
// 64-key tiles; K-split over blockIdx.z (1024 keys each).
__global__ __launch_bounds__(256, 2) void attn_kernel(const u16* __restrict__ QT,
                                                      const u16* __restrict__ KTm,
                                                      const u16* __restrict__ Vc,
                                                      u16* __restrict__ Op,
                                                      float* __restrict__ Lp) {
    const int head = blockIdx.y, split = blockIdx.z;
    const int qb   = blockIdx.x * 128;
    const int tid  = threadIdx.x;
    const int wave = tid >> 6, lane = tid & 63;
    const int quad = lane >> 4, low = lane & 15;

    const u16* Qh = QT  + head * N_TOK * 64;
    const u16* Kh = KTm + head * N_TOK * 64 + split * 1024 * 64;
    const u16* Vh = Vc  + head * 64 * N_TOK + split * 1024;

    __shared__ u16 Ks[2][64 * 64];   // [s][c], 8-short chunks XOR-swizzled by s&7
    __shared__ u16 Vs[2][64 * 64];   // [c][s], swizzled by c&7
    __shared__ u16 Ps[4 * 32 * 64];  // per-wave [t][s], swizzled by t&7
    u16* Pw = Ps + wave * 2048;

    bf16x8 ones;
#pragma unroll
    for (int i = 0; i < 8; ++i) ones[i] = (short)0x3F80;

    // Q B-fragments (n=t, k=c), loaded once (scale+log2e folded into Q weights)
    bf16x8 bq[2][2];
#pragma unroll
    for (int tn = 0; tn < 2; ++tn)
#pragma unroll
        for (int kh = 0; kh < 2; ++kh)
            bq[tn][kh] = *(const bf16x8*)(Qh + (qb + wave * 32 + tn * 16 + low) * 64 + kh * 32 + quad * 8);

    f32x4 oa[2][4], lC[2];
#pragma unroll
    for (int mt = 0; mt < 2; ++mt) {
        lC[mt] = f32x4{0,0,0,0};
#pragma unroll
        for (int cn = 0; cn < 4; ++cn) oa[mt][cn] = f32x4{0,0,0,0};
    }

    // staging: 512 16B chunks each; thread owns rows sA, sA+32, chunk gA
    const int sA = tid >> 3, gA = tid & 7;
    const int swA = ((gA ^ (sA & 7)) * 8);
    const int swB = ((gA ^ ((sA + 32) & 7)) * 8);
    uint4 pk0 = *(const uint4*)(Kh + sA * 64 + gA * 8);
    uint4 pk1 = *(const uint4*)(Kh + (sA + 32) * 64 + gA * 8);
    uint4 pv0 = *(const uint4*)(Vh + sA * N_TOK + gA * 8);
    uint4 pv1 = *(const uint4*)(Vh + (sA + 32) * N_TOK + gA * 8);
    *(uint4*)(Ks[0] + sA * 64 + swA) = pk0;
    *(uint4*)(Ks[0] + (sA + 32) * 64 + swB) = pk1;
    *(uint4*)(Vs[0] + sA * 64 + swA) = pv0;
    *(uint4*)(Vs[0] + (sA + 32) * 64 + swB) = pv1;
    pk0 = *(const uint4*)(Kh + (64 + sA) * 64 + gA * 8);
    pk1 = *(const uint4*)(Kh + (64 + sA + 32) * 64 + gA * 8);
    pv0 = *(const uint4*)(Vh + sA * N_TOK + 64 + gA * 8);
    pv1 = *(const uint4*)(Vh + (sA + 32) * N_TOK + 64 + gA * 8);

    const int low7 = low & 7;

    for (int kt = 0; kt < 16; ++kt) {
        const int cur = kt & 1;
        const u16* Kc = Ks[cur];
        const u16* Vu = Vs[cur];
        __syncthreads();   // buf[cur] staged & visible; prior reads of buf[cur^1] done
        if (kt < 15) {     // write prefetched tile kt+1 into the other buffer
            u16* Kn = Ks[cur ^ 1]; u16* Vn = Vs[cur ^ 1];
            *(uint4*)(Kn + sA * 64 + swA) = pk0;
            *(uint4*)(Kn + (sA + 32) * 64 + swB) = pk1;
            *(uint4*)(Vn + sA * 64 + swA) = pv0;
            *(uint4*)(Vn + (sA + 32) * 64 + swB) = pv1;
            if (kt < 14) { // issue loads for tile kt+2
                int sb2 = (kt + 2) * 64;
                pk0 = *(const uint4*)(Kh + (sb2 + sA) * 64 + gA * 8);
                pk1 = *(const uint4*)(Kh + (sb2 + sA + 32) * 64 + gA * 8);
                pv0 = *(const uint4*)(Vh + sA * N_TOK + sb2 + gA * 8);
                pv1 = *(const uint4*)(Vh + (sA + 32) * N_TOK + sb2 + gA * 8);
            }
        }

        // ---- S^T: C[m=s][n=t] = K A-frag x Q B-frag --------------------------
        f32x4 sa[4][2];
#pragma unroll
        for (int sm = 0; sm < 4; ++sm)
#pragma unroll
            for (int tn = 0; tn < 2; ++tn) sa[sm][tn] = f32x4{0,0,0,0};
#pragma unroll
        for (int kh = 0; kh < 2; ++kh)
#pragma unroll
            for (int sm = 0; sm < 4; ++sm) {
                bf16x8 ak = *(const bf16x8*)(Kc + (sm * 16 + low) * 64 + (((quad + 4 * kh) ^ low7) * 8));
#pragma unroll
                for (int tn = 0; tn < 2; ++tn)
                    sa[sm][tn] = __builtin_amdgcn_mfma_f32_16x16x32_bf16(ak, bq[tn][kh], sa[sm][tn], 0, 0, 0);
            }

        // ---- P = exp2(S) (log2e pre-folded), packed b64 stores into Pw[t][s]
#pragma unroll
        for (int sm = 0; sm < 4; ++sm)
#pragma unroll
            for (int tn = 0; tn < 2; ++tn) {
                float p0 = exp2f(sa[sm][tn][0]);
                float p1 = exp2f(sa[sm][tn][1]);
                float p2 = exp2f(sa[sm][tn][2]);
                float p3 = exp2f(sa[sm][tn][3]);
                uint2 pk; pk.x = packtr(p0, p1); pk.y = packtr(p2, p3);
                int t = tn * 16 + low;
                int sw = ((sm * 2 + (quad >> 1)) ^ low7);
                *(uint2*)(Pw + t * 64 + sw * 8 + (quad & 1) * 4) = pk;
            }
        asm volatile("s_waitcnt lgkmcnt(0)" ::: "memory");  // wave-private P round-trip

        // ---- O += P V^T, l += P 1 ----
#pragma unroll
        for (int kh = 0; kh < 2; ++kh) {
            bf16x8 ap0 = *(const bf16x8*)(Pw + (low) * 64      + (((quad + 4 * kh) ^ low7) * 8));
            bf16x8 ap1 = *(const bf16x8*)(Pw + (16 + low) * 64 + (((quad + 4 * kh) ^ low7) * 8));
            lC[0] = __builtin_amdgcn_mfma_f32_16x16x32_bf16(ap0, ones, lC[0], 0, 0, 0);
            lC[1] = __builtin_amdgcn_mfma_f32_16x16x32_bf16(ap1, ones, lC[1], 0, 0, 0);
#pragma unroll
            for (int cn = 0; cn < 4; ++cn) {
                bf16x8 bv = *(const bf16x8*)(Vu + (cn * 16 + low) * 64 + (((quad + 4 * kh) ^ low7) * 8));
                oa[0][cn] = __builtin_amdgcn_mfma_f32_16x16x32_bf16(ap0, bv, oa[0][cn], 0, 0, 0);
                oa[1][cn] = __builtin_amdgcn_mfma_f32_16x16x32_bf16(ap1, bv, oa[1][cn], 0, 0, 0);
            }
        }
    }

    // ---- epilogue: partials (terminal scatters retire with the wave — cheap)
    const int sh = (split * 4 + head) * N_TOK;
#pragma unroll
    for (int mt = 0; mt < 2; ++mt)
#pragma unroll
        for (int r = 0; r < 4; ++r) {
            int t = qb + wave * 32 + mt * 16 + quad * 4 + r;
            if (low == 0) Lp[sh + t] = lC[mt][r];
#pragma unroll
            for (int cn = 0; cn < 4; ++cn)
                Op[(sh + t) * 64 + cn * 16 + low] = f2bf(oa[mt][cn][r]);
        }
}

// ---------------- L4: combine partials (into LDS hT tile) + proj GEMM + bias
// ---------------- + residual (fp32 out). 32-token x 128-row tiles (y=2 ->
// ---------------- combine redundancy 2x; 256 blocks keeps all CUs engaged).
__global__ __launch_bounds__(256) void proj_gemm(const u16* __restrict__ wp,
                                                 const u16* __restrict__ Op,
                                                 const float* __restrict__ Lp,
                                                 const float* __restrict__ bias,
                                                 const float* __restrict__ xres,
                                                 float* __restrict__ out) {
    const int nb = blockIdx.x * 32;
    const int mo = blockIdx.y * 128 + (threadIdx.x >> 6) * 32;
    const int lane = threadIdx.x & 63;
    const int quad = lane >> 4, low = lane & 15;

    __shared__ u16 hT[32 * 264];   // [t][c], row stride 264 shorts -> 2-way banks, free

    // combine: 1024 chunks (32 tok x 32 eight-channel chunks), 4 per thread
#pragma unroll
    for (int i = 0; i < 4; ++i) {
        int idx = i * 256 + threadIdx.x;
        int t = idx >> 5, cc = idx & 31;
        int head = cc >> 3;
        int tok = nb + t;
        float l = 0.f;
        float o[8] = {0.f,0.f,0.f,0.f,0.f,0.f,0.f,0.f};
#pragma unroll
        for (int sp = 0; sp < SPLITS; ++sp) {
            int b = (sp * 4 + head) * N_TOK + tok;
            l += Lp[b];
            uint4 pv = *(const uint4*)(Op + b * 64 + (cc & 7) * 8);
            const u16* ps = (const u16*)&pv;
#pragma unroll
            for (int j = 0; j < 8; ++j) o[j] += bf2f(ps[j]);
        }
        float rl = 1.f / l;
        u16 res[8];
#pragma unroll
        for (int j = 0; j < 8; ++j) res[j] = f2bf(o[j] * rl);
        *(uint4*)(hT + t * 264 + cc * 8) = *(const uint4*)res;
    }
    __syncthreads();

    f32x4 acc[2][2] = {{f32x4{0,0,0,0}, f32x4{0,0,0,0}}, {f32x4{0,0,0,0}, f32x4{0,0,0,0}}};
#pragma unroll
    for (int kc = 0; kc < 8; ++kc) {
        bf16x8 b0 = *(const bf16x8*)(hT + (low) * 264      + kc * 32 + quad * 8);
        bf16x8 b1 = *(const bf16x8*)(hT + (16 + low) * 264 + kc * 32 + quad * 8);
#pragma unroll
        for (int mt = 0; mt < 2; ++mt) {
            bf16x8 af = *(const bf16x8*)(wp + (mo + mt * 16 + low) * 256 + kc * 32 + quad * 8);
            acc[mt][0] = __builtin_amdgcn_mfma_f32_16x16x32_bf16(af, b0, acc[mt][0], 0, 0, 0);
            acc[mt][1] = __builtin_amdgcn_mfma_f32_16x16x32_bf16(af, b1, acc[mt][1], 0, 0, 0);
        }
    }
#pragma unroll
    for (int mt = 0; mt < 2; ++mt)
#pragma unroll
        for (int r = 0; r < 4; ++r) {
            int o = mo + mt * 16 + quad * 4 + r;
            float bv = bias[o];
#pragma unroll
            for (int nt = 0; nt < 2; ++nt) {
                int tok = nb + nt * 16 + low;
                out[o * N_TOK + tok] = acc[mt][nt][r] + bv + xres[o * N_TOK + tok];
            }
        }
}

extern "C" void kernel_launch(void* const* d_in, const int* in_sizes, int n_in,
                              void* d_out, int out_size, void* d_ws, size_t ws_size,
                              hipStream_t stream) {
    const float* x      = (const float*)d_in[0];
    const float* gamma  = (const float*)d_in[1];
    const float* beta   = (const float*)d_in[2];
    const float* w_qkv  = (const float*)d_in[3];
    const float* w_proj = (const float*)d_in[4];
    const float* b_proj = (const float*)d_in[5];
    float* out = (float*)d_out;

    // ws layout (bytes).
    char* base = (char*)d_ws;
    u16*    Op    = (u16*)base;                        // 4*4*4096*64*2  = 8,388,608
    float*  Lp    = (float*)(base + 8388608);          // 4*4*4096*4     =   262,144
    float2* part  = (float2*)(base + 8654848);         // 4 KB
    u16*    wq    = (u16*)(base + 8658944);            // 768*256*2      =   393,216
    u16*    wp    = (u16*)(base + 9052160);            // 256*256*2      =   131,072
    u16*    QT    = (u16*)(base + 9183232);            // 2 MB
    u16*    KTm   = (u16*)(base + 11280384);           // 2 MB
    u16*    Vc    = (u16*)(base + 13377536);           // 2 MB (end ~15.5 MB)

    prep      <<<1280, 256, 0, stream>>>(w_qkv, w_proj, x, wq, wp, part);
    qkv_gemm  <<<dim3(64, 12), 256, 0, stream>>>(wq, x, part, gamma, beta, QT, KTm, Vc);
    attn_kernel<<<dim3(32, 4, SPLITS), 256, 0, stream>>>(QT, KTm, Vc, Op, Lp);
    proj_gemm <<<dim3(128, 2), 256, 0, stream>>>(wp, Op, Lp, b_proj, x, out);
}

// Round 6
// 118.120 us; speedup vs baseline: 1.0573x; 1.0076x over previous
//
#include <hip/hip_runtime.h>
#include <math.h>

// B=1, C=256, N=16^3=4096 tokens, 16 groups, 4 heads, d=64.
#define N_TOK 4096
#define C_CH  256
#define SPLITS 4

typedef short bf16x8 __attribute__((ext_vector_type(8)));
typedef float f32x4  __attribute__((ext_vector_type(4)));
typedef unsigned short u16;

__device__ __forceinline__ u16 f2bf(float f) {
    union { float f; unsigned u; } v; v.f = f;
    unsigned r = v.u + 0x7FFF + ((v.u >> 16) & 1);   // RNE
    return (u16)(r >> 16);
}
__device__ __forceinline__ float bf2f(u16 b) {
    union { unsigned u; float f; } v; v.u = ((unsigned)b) << 16;
    return v.f;
}
// pack two floats to bf16 pair (truncation) in one v_perm_b32
__device__ __forceinline__ unsigned packtr(float a, float b) {
    union { float f; unsigned u; } ua, ub; ua.f = a; ub.f = b;
    return __builtin_amdgcn_perm(ub.u, ua.u, 0x07060302u);  // lo=hi16(a), hi=hi16(b)
}

// ---------------- L1: weight convert (blocks 0..1023) + GN partials (1024..1279)
// Q rows pre-scaled by 1/8 (qk scale) * log2(e) (exp->exp2 fold).
__global__ __launch_bounds__(256) void prep(const float* __restrict__ wqkv,
                                            const float* __restrict__ wproj,
                                            const float* __restrict__ x,
                                            u16* __restrict__ wq, u16* __restrict__ wp,
                                            float2* __restrict__ part) {
    __shared__ float rs[4], rss[4];
    if (blockIdx.x < 1024) {
        int i = blockIdx.x * 256 + threadIdx.x;          // 262144 threads
        if (i < 196608) {
            int row = i >> 8;
            float s = ((row % 192) < 64) ? 0.18033688f : 1.0f;  // 0.125*log2(e) for Q
            wq[i] = f2bf(wqkv[i] * s);
        } else {
            wp[i - 196608] = f2bf(wproj[i - 196608]);
        }
    } else {
        const int b = blockIdx.x - 1024, tid = threadIdx.x;
        const int lane = tid & 63, wave = tid >> 6;
        const float4* xp = (const float4*)x + b * 1024;
        float s = 0.f, ss = 0.f;
#pragma unroll
        for (int k = 0; k < 4; ++k) {
            float4 v = xp[tid + k * 256];
            s  += v.x + v.y + v.z + v.w;
            ss += v.x * v.x + v.y * v.y + v.z * v.z + v.w * v.w;
        }
#pragma unroll
        for (int off = 1; off < 64; off <<= 1) {
            s  += __shfl_xor(s, off, 64);
            ss += __shfl_xor(ss, off, 64);
        }
        if (lane == 0) { rs[wave] = s; rss[wave] = ss; }
        __syncthreads();
        if (tid == 0) part[b] = make_float2(rs[0]+rs[1]+rs[2]+rs[3], rss[0]+rss[1]+rss[2]+rss[3]);
    }
}

// ---------------- L2: fused GroupNorm + QKV GEMM ----------------------------
// Stages the normalized/transposed 64-tok x 256-ch B-panel once in LDS
// (XOR-swizzled), then MFMA against bf16 weights. Each blockIdx.y produces one
// clean 64x64 tile for exactly one of QT/KTm/Vc: y%3 = Q/K/V, y/3 = head,
// in-block row = c. Q/K: packed uint2 stores; V: LDS transpose + uint4 stores.
__global__ __launch_bounds__(256) void qkv_gemm(const u16* __restrict__ wq,
                                                const float* __restrict__ x,
                                                const float2* __restrict__ part,
                                                const float* __restrict__ gamma,
                                                const float* __restrict__ beta,
                                                u16* __restrict__ QT,
                                                u16* __restrict__ KTm,
                                                u16* __restrict__ Vc) {
    const int nb = blockIdx.x * 64;
    const int tid = threadIdx.x;
    const int wave = tid >> 6, lane = tid & 63;
    const int quad = lane >> 4, low = lane & 15;
    const int mo = blockIdx.y * 64 + wave * 16;

    __shared__ __align__(16) u16 Xs[64 * 256];  // [tok][ch], XOR-swizzled by tok&7
    __shared__ float sca[256], scb[256];

    {   // per-channel affine: a = rstd*gamma, b = beta - mu*a (redundant per block)
        const int ch = tid, g = ch >> 4;
        float s = 0.f, ss = 0.f;
#pragma unroll
        for (int j = 0; j < 16; ++j) { float2 p = part[g * 16 + j]; s += p.x; ss += p.y; }
        float mu = s * (1.f / 65536.f);
        float var = ss * (1.f / 65536.f) - mu * mu;
        float a = rsqrtf(var + 1e-5f) * gamma[ch];
        sca[ch] = a; scb[ch] = beta[ch] - mu * a;
    }
    __syncthreads();

    // stage: thread owns token=lane, channel-groups wave*8+i (i<8); 8-ch chunk each
#pragma unroll
    for (int i = 0; i < 8; ++i) {
        const int g = wave * 8 + i;               // 0..31
        u16 pk[8];
#pragma unroll
        for (int j = 0; j < 8; ++j) {
            const int ch = g * 8 + j;
            pk[j] = f2bf(x[ch * N_TOK + nb + lane] * sca[ch] + scb[ch]);
        }
        *(uint4*)(Xs + lane * 256 + ((g ^ (lane & 7)) * 8)) = *(const uint4*)pk;
    }
    __syncthreads();

    f32x4 acc[4] = {f32x4{0,0,0,0}, f32x4{0,0,0,0}, f32x4{0,0,0,0}, f32x4{0,0,0,0}};
#pragma unroll
    for (int kc = 0; kc < 8; ++kc) {
        bf16x8 af = *(const bf16x8*)(wq + (mo + low) * 256 + kc * 32 + quad * 8);
#pragma unroll
        for (int nt = 0; nt < 4; ++nt) {
            bf16x8 bf_ = *(const bf16x8*)(Xs + (nt * 16 + low) * 256 +
                                          (((kc * 4 + quad) ^ (low & 7)) * 8));
            acc[nt] = __builtin_amdgcn_mfma_f32_16x16x32_bf16(af, bf_, acc[nt], 0, 0, 0);
        }
    }

    // ---- epilogue: one 64x64 tile per block ----
    const int kind = blockIdx.y % 3;              // 0=Q, 1=K, 2=V
    const int head = blockIdx.y / 3;
    const int crow = wave * 16 + quad * 4;        // in-block output row (= c)

    if (kind < 2) {
        // token-major [head][tok][c]: 4 consecutive c per thread -> uint2 store
        u16* dst = (kind == 0 ? QT : KTm) + head * (N_TOK * 64);
#pragma unroll
        for (int nt = 0; nt < 4; ++nt) {
            int tok = nb + nt * 16 + low;
            u16 q4[4];
#pragma unroll
            for (int r = 0; r < 4; ++r) q4[r] = f2bf(acc[nt][r]);
            *(uint2*)(dst + tok * 64 + crow) = *(const uint2*)q4;
        }
    } else {
        // channel-major [head][c][tok]: transpose through LDS, coalesced uint4 out
        __syncthreads();                          // Xs MFMA reads complete
        u16* Ts = Xs;                             // reuse as [64][72] (144B rows, 16B-aligned)
#pragma unroll
        for (int nt = 0; nt < 4; ++nt) {
            int tokl = nt * 16 + low;
#pragma unroll
            for (int r = 0; r < 4; ++r)
                Ts[(crow + r) * 72 + tokl] = f2bf(acc[nt][r]);
        }
        __syncthreads();
        u16* dst = Vc + head * (64 * N_TOK) + nb;
#pragma unroll
        for (int i = 0; i < 2; ++i) {
            int idx = i * 256 + tid;
            int c = idx >> 3, ch = idx & 7;
            uint4 v = *(const uint4*)(Ts + c * 72 + ch * 8);
            *(uint4*)(dst + c * N_TOK + ch * 8) = v;
        }
    }
}

// ---------------- L3: flash-lite attention, exp2 softmax, l via ones-MFMA ---
// Double-buffered K/V staging, ONE barrier per tile. P never leaves registers:
// PV uses a slot-permuted contraction — slot (kh,quad,j) holds
// s = 32*kh + 16*(j>>2) + 4*quad + (j&3) — so the A-frag is a lane-local pack
// of the QK^T C-fragment and the B-frag is two b64 reads of Vs. Contraction is
// slot-permutation-invariant since A and B agree on the permutation.
__global__ __launch_bounds__(256, 2) void attn_kernel(const u16* __restrict__ QT,
                                                      const u16* __restrict__ KTm,
                                                      const u16* __restrict__ Vc,
                                                      u16* __restrict__ Op,
                                                      float* __restrict__ Lp) {
    const int head = blockIdx.y, split = blockIdx.z;
    const int qb   = blockIdx.x * 128;
    const int tid  = threadIdx.x;
    const int wave = tid >> 6, lane = tid & 63;
    const int quad = lane >> 4, low = lane & 15;

    const u16* Qh = QT  + head * N_TOK * 64;
    const u16* Kh = KTm + head * N_TOK * 64 + split * 1024 * 64;
    const u16* Vh = Vc  + head * 64 * N_TOK + split * 1024;

    __shared__ u16 Ks[2][64 * 64];   // [s][c], 8-short chunks XOR-swizzled by s&7
    __shared__ u16 Vs[2][64 * 64];   // [c][s], swizzled by c&7

    bf16x8 ones;
#pragma unroll
    for (int i = 0; i < 8; ++i) ones[i] = (short)0x3F80;

    // Q B-fragments (n=t, k=c), loaded once (scale+log2e folded into Q weights)
    bf16x8 bq[2][2];
#pragma unroll
    for (int tn = 0; tn < 2; ++tn)
#pragma unroll
        for (int kh = 0; kh < 2; ++kh)
            bq[tn][kh] = *(const bf16x8*)(Qh + (qb + wave * 32 + tn * 16 + low) * 64 + kh * 32 + quad * 8);

    f32x4 oa[2][4], lC[2];
#pragma unroll
    for (int mt = 0; mt < 2; ++mt) {
        lC[mt] = f32x4{0,0,0,0};
#pragma unroll
        for (int cn = 0; cn < 4; ++cn) oa[mt][cn] = f32x4{0,0,0,0};
    }

    // staging: 512 16B chunks each; thread owns rows sA, sA+32, chunk gA
    const int sA = tid >> 3, gA = tid & 7;
    const int swA = ((gA ^ (sA & 7)) * 8);
    const int swB = ((gA ^ ((sA + 32) & 7)) * 8);
    uint4 pk0 = *(const uint4*)(Kh + sA * 64 + gA * 8);
    uint4 pk1 = *(const uint4*)(Kh + (sA + 32) * 64 + gA * 8);
    uint4 pv0 = *(const uint4*)(Vh + sA * N_TOK + gA * 8);
    uint4 pv1 = *(const uint4*)(Vh + (sA + 32) * N_TOK + gA * 8);
    *(uint4*)(Ks[0] + sA * 64 + swA) = pk0;
    *(uint4*)(Ks[0] + (sA + 32) * 64 + swB) = pk1;
    *(uint4*)(Vs[0] + sA * 64 + swA) = pv0;
    *(uint4*)(Vs[0] + (sA + 32) * 64 + swB) = pv1;
    pk0 = *(const uint4*)(Kh + (64 + sA) * 64 + gA * 8);
    pk1 = *(const uint4*)(Kh + (64 + sA + 32) * 64 + gA * 8);
    pv0 = *(const uint4*)(Vh + sA * N_TOK + 64 + gA * 8);
    pv1 = *(const uint4*)(Vh + (sA + 32) * N_TOK + 64 + gA * 8);

    const int low7 = low & 7;

    for (int kt = 0; kt < 16; ++kt) {
        const int cur = kt & 1;
        const u16* Kc = Ks[cur];
        const u16* Vu = Vs[cur];
        __syncthreads();   // buf[cur] staged & visible; prior reads of buf[cur^1] done
        if (kt < 15) {     // write prefetched tile kt+1 into the other buffer
            u16* Kn = Ks[cur ^ 1]; u16* Vn = Vs[cur ^ 1];
            *(uint4*)(Kn + sA * 64 + swA) = pk0;
            *(uint4*)(Kn + (sA + 32) * 64 + swB) = pk1;
            *(uint4*)(Vn + sA * 64 + swA) = pv0;
            *(uint4*)(Vn + (sA + 32) * 64 + swB) = pv1;
            if (kt < 14) { // issue loads for tile kt+2
                int sb2 = (kt + 2) * 64;
                pk0 = *(const uint4*)(Kh + (sb2 + sA) * 64 + gA * 8);
                pk1 = *(const uint4*)(Kh + (sb2 + sA + 32) * 64 + gA * 8);
                pv0 = *(const uint4*)(Vh + sA * N_TOK + sb2 + gA * 8);
                pv1 = *(const uint4*)(Vh + (sA + 32) * N_TOK + sb2 + gA * 8);
            }
        }

        // ---- S^T: C[m=s][n=t] = K A-frag x Q B-frag --------------------------
        f32x4 sa[4][2];
#pragma unroll
        for (int sm = 0; sm < 4; ++sm)
#pragma unroll
            for (int tn = 0; tn < 2; ++tn) sa[sm][tn] = f32x4{0,0,0,0};
#pragma unroll
        for (int kh = 0; kh < 2; ++kh)
#pragma unroll
            for (int sm = 0; sm < 4; ++sm) {
                bf16x8 ak = *(const bf16x8*)(Kc + (sm * 16 + low) * 64 + (((quad + 4 * kh) ^ low7) * 8));
#pragma unroll
                for (int tn = 0; tn < 2; ++tn)
                    sa[sm][tn] = __builtin_amdgcn_mfma_f32_16x16x32_bf16(ak, bq[tn][kh], sa[sm][tn], 0, 0, 0);
            }

        // ---- P = exp2(S), packed lane-locally into slot-permuted A-frags ----
        // ap[tn][kh] slot j: j<4 -> sa[2kh][tn][j&3], j>=4 -> sa[2kh+1][tn][j&3]
        bf16x8 ap[2][2];
#pragma unroll
        for (int tn = 0; tn < 2; ++tn)
#pragma unroll
            for (int kh = 0; kh < 2; ++kh) {
                union { bf16x8 v; unsigned w[4]; } u;
                u.w[0] = packtr(exp2f(sa[2*kh][tn][0]),     exp2f(sa[2*kh][tn][1]));
                u.w[1] = packtr(exp2f(sa[2*kh][tn][2]),     exp2f(sa[2*kh][tn][3]));
                u.w[2] = packtr(exp2f(sa[2*kh+1][tn][0]),   exp2f(sa[2*kh+1][tn][1]));
                u.w[3] = packtr(exp2f(sa[2*kh+1][tn][2]),   exp2f(sa[2*kh+1][tn][3]));
                ap[tn][kh] = u.v;
            }

        // ---- O += P V^T, l += P 1 (B-frag gathers the permuted V rows) ----
#pragma unroll
        for (int kh = 0; kh < 2; ++kh) {
            lC[0] = __builtin_amdgcn_mfma_f32_16x16x32_bf16(ap[0][kh], ones, lC[0], 0, 0, 0);
            lC[1] = __builtin_amdgcn_mfma_f32_16x16x32_bf16(ap[1][kh], ones, lC[1], 0, 0, 0);
#pragma unroll
            for (int cn = 0; cn < 4; ++cn) {
                int c = cn * 16 + low;
                union { bf16x8 v; uint2 u[2]; } bv;
                bv.u[0] = *(const uint2*)(Vu + c * 64 + (((4*kh     + (quad >> 1)) ^ low7) * 8) + (quad & 1) * 4);
                bv.u[1] = *(const uint2*)(Vu + c * 64 + (((4*kh + 2 + (quad >> 1)) ^ low7) * 8) + (quad & 1) * 4);
                oa[0][cn] = __builtin_amdgcn_mfma_f32_16x16x32_bf16(ap[0][kh], bv.v, oa[0][cn], 0, 0, 0);
                oa[1][cn] = __builtin_amdgcn_mfma_f32_16x16x32_bf16(ap[1][kh], bv.v, oa[1][cn], 0, 0, 0);
            }
        }
    }

    // ---- epilogue: partials (terminal scatters retire with the wave — cheap)
    const int sh = (split * 4 + head) * N_TOK;
#pragma unroll
    for (int mt = 0; mt < 2; ++mt)
#pragma unroll
        for (int r = 0; r < 4; ++r) {
            int t = qb + wave * 32 + mt * 16 + quad * 4 + r;
            if (low == 0) Lp[sh + t] = lC[mt][r];
#pragma unroll
            for (int cn = 0; cn < 4; ++cn)
                Op[(sh + t) * 64 + cn * 16 + low] = f2bf(oa[mt][cn][r]);
        }
}

// ---------------- L4: combine partials (into LDS hT tile) + proj GEMM + bias
// ---------------- + residual (fp32 out). 32-token x 128-row tiles (y=2 ->
// ---------------- combine redundancy 2x; 256 blocks keeps all CUs engaged).
__global__ __launch_bounds__(256) void proj_gemm(const u16* __restrict__ wp,
                                                 const u16* __restrict__ Op,
                                                 const float* __restrict__ Lp,
                                                 const float* __restrict__ bias,
                                                 const float* __restrict__ xres,
                                                 float* __restrict__ out) {
    const int nb = blockIdx.x * 32;
    const int mo = blockIdx.y * 128 + (threadIdx.x >> 6) * 32;
    const int lane = threadIdx.x & 63;
    const int quad = lane >> 4, low = lane & 15;

    __shared__ u16 hT[32 * 264];   // [t][c], row stride 264 shorts -> 2-way banks, free

    // combine: 1024 chunks (32 tok x 32 eight-channel chunks), 4 per thread
#pragma unroll
    for (int i = 0; i < 4; ++i) {
        int idx = i * 256 + threadIdx.x;
        int t = idx >> 5, cc = idx & 31;
        int head = cc >> 3;
        int tok = nb + t;
        float l = 0.f;
        float o[8] = {0.f,0.f,0.f,0.f,0.f,0.f,0.f,0.f};
#pragma unroll
        for (int sp = 0; sp < SPLITS; ++sp) {
            int b = (sp * 4 + head) * N_TOK + tok;
            l += Lp[b];
            uint4 pv = *(const uint4*)(Op + b * 64 + (cc & 7) * 8);
            const u16* ps = (const u16*)&pv;
#pragma unroll
            for (int j = 0; j < 8; ++j) o[j] += bf2f(ps[j]);
        }
        float rl = 1.f / l;
        u16 res[8];
#pragma unroll
        for (int j = 0; j < 8; ++j) res[j] = f2bf(o[j] * rl);
        *(uint4*)(hT + t * 264 + cc * 8) = *(const uint4*)res;
    }
    __syncthreads();

    f32x4 acc[2][2] = {{f32x4{0,0,0,0}, f32x4{0,0,0,0}}, {f32x4{0,0,0,0}, f32x4{0,0,0,0}}};
#pragma unroll
    for (int kc = 0; kc < 8; ++kc) {
        bf16x8 b0 = *(const bf16x8*)(hT + (low) * 264      + kc * 32 + quad * 8);
        bf16x8 b1 = *(const bf16x8*)(hT + (16 + low) * 264 + kc * 32 + quad * 8);
#pragma unroll
        for (int mt = 0; mt < 2; ++mt) {
            bf16x8 af = *(const bf16x8*)(wp + (mo + mt * 16 + low) * 256 + kc * 32 + quad * 8);
            acc[mt][0] = __builtin_amdgcn_mfma_f32_16x16x32_bf16(af, b0, acc[mt][0], 0, 0, 0);
            acc[mt][1] = __builtin_amdgcn_mfma_f32_16x16x32_bf16(af, b1, acc[mt][1], 0, 0, 0);
        }
    }
#pragma unroll
    for (int mt = 0; mt < 2; ++mt)
#pragma unroll
        for (int r = 0; r < 4; ++r) {
            int o = mo + mt * 16 + quad * 4 + r;
            float bv = bias[o];
#pragma unroll
            for (int nt = 0; nt < 2; ++nt) {
                int tok = nb + nt * 16 + low;
                out[o * N_TOK + tok] = acc[mt][nt][r] + bv + xres[o * N_TOK + tok];
            }
        }
}

extern "C" void kernel_launch(void* const* d_in, const int* in_sizes, int n_in,
                              void* d_out, int out_size, void* d_ws, size_t ws_size,
                              hipStream_t stream) {
    const float* x      = (const float*)d_in[0];
    const float* gamma  = (const float*)d_in[1];
    const float* beta   = (const float*)d_in[2];
    const float* w_qkv  = (const float*)d_in[3];
    const float* w_proj = (const float*)d_in[4];
    const float* b_proj = (const float*)d_in[5];
    float* out = (float*)d_out;

    // ws layout (bytes).
    char* base = (char*)d_ws;
    u16*    Op    = (u16*)base;                        // 4*4*4096*64*2  = 8,388,608
    float*  Lp    = (float*)(base + 8388608);          // 4*4*4096*4     =   262,144
    float2* part  = (float2*)(base + 8654848);         // 4 KB
    u16*    wq    = (u16*)(base + 8658944);            // 768*256*2      =   393,216
    u16*    wp    = (u16*)(base + 9052160);            // 256*256*2      =   131,072
    u16*    QT    = (u16*)(base + 9183232);            // 2 MB
    u16*    KTm   = (u16*)(base + 11280384);           // 2 MB
    u16*    Vc    = (u16*)(base + 13377536);           // 2 MB (end ~15.5 MB)

    prep      <<<1280, 256, 0, stream>>>(w_qkv, w_proj, x, wq, wp, part);
    qkv_gemm  <<<dim3(64, 12), 256, 0, stream>>>(wq, x, part, gamma, beta, QT, KTm, Vc);
    attn_kernel<<<dim3(32, 4, SPLITS), 256, 0, stream>>>(QT, KTm, Vc, Op, Lp);
    proj_gemm <<<dim3(128, 2), 256, 0, stream>>>(wp, Op, Lp, b_proj, x, out);
}